// Round 9
// baseline (333.721 us; speedup 1.0000x reference)
//
#include <hip/hip_runtime.h>
#include <math.h>

// Problem constants (inputs/outputs are f32; verified round 4)
#define NTOK  16384   // B*T
#define DDIM  1024
#define NDOCS 4096
#define NSLICE 8            // doc slices for topk_part
#define SLICE (NDOCS/NSLICE)  // 512 docs per slice
#define TOPL  6             // per-lane candidate list length
#define KPT   64            // candidate keys per token (8 slices x top-8)
#define MN20  (1u<<20)      // 1024*1024

typedef __attribute__((ext_vector_type(8))) short short8;
typedef __attribute__((ext_vector_type(4))) float f32x4;

__device__ __forceinline__ float b2f(unsigned short u){
  union { unsigned int i; float f; } v; v.i = ((unsigned int)u) << 16; return v.f;
}
__device__ __forceinline__ unsigned short f2b(float f){
  union { float f; unsigned int i; } v; v.f = f;
  unsigned int r = v.i + 0x7fffu + ((v.i >> 16) & 1u);   // RNE
  return (unsigned short)(r >> 16);
}
// async global->LDS, 16B per lane: LDS dest = wave-uniform base + lane*16
__device__ __forceinline__ void gld16(const void* g, void* l){
  __builtin_amdgcn_global_load_lds(
      (const __attribute__((address_space(1))) void*)g,
      (__attribute__((address_space(3))) void*)l, 16, 0, 0);
}
// sorted-desc top-TOPL insert: keys[k] = median(keys[k-1], keys[k], key).
__device__ __forceinline__ void kinsert(unsigned int* keys, unsigned int key){
  #pragma unroll
  for (int k = TOPL-1; k >= 1; --k){
    unsigned int lo = keys[k-1] < key ? keys[k-1] : key;
    keys[k] = keys[k] > lo ? keys[k] : lo;
  }
  keys[0] = keys[0] > key ? keys[0] : key;
}
__device__ __forceinline__ void ceswap(unsigned int& a, unsigned int& b){
  unsigned int mx = a > b ? a : b, mn = a > b ? b : a; a = mx; b = mn;
}
// sort a bitonic 8-sequence descending (3 half-cleaner stages, 12 CE)
__device__ __forceinline__ void bitonic8(unsigned int* c){
  ceswap(c[0],c[4]); ceswap(c[1],c[5]); ceswap(c[2],c[6]); ceswap(c[3],c[7]);
  ceswap(c[0],c[2]); ceswap(c[1],c[3]); ceswap(c[4],c[6]); ceswap(c[5],c[7]);
  ceswap(c[0],c[1]); ceswap(c[2],c[3]); ceswap(c[4],c[5]); ceswap(c[6],c[7]);
}

// ---------------------------------------------------------------------------
// prep_kernel: all independent preprocessing in one launch (block ranges):
//  [0,4096) cast dvals->dv16; [4096,5120) cast Wdoc->wd16;
//  [5120,6144) transpose Wv->T1; [6144,7168) transpose Wo->T2;
//  [7168,7184) bc = bv@Wo + bo
// ---------------------------------------------------------------------------
__global__ __launch_bounds__(256)
void prep_kernel(const float* __restrict__ dvals, unsigned short* __restrict__ dv16,
                 const float* __restrict__ Wdoc,  unsigned short* __restrict__ wd16,
                 const float* __restrict__ Wv,    unsigned short* __restrict__ T1,
                 const float* __restrict__ Wo,    unsigned short* __restrict__ T2,
                 const float* __restrict__ bv, const float* __restrict__ bo,
                 float* __restrict__ bc){
  __shared__ unsigned short t[32][33];
  __shared__ float part[4][64];
  int bx = blockIdx.x, tid = threadIdx.x;
  if (bx < 5120){
    const float* in        = bx < 4096 ? dvals : Wdoc;
    unsigned short* outp   = bx < 4096 ? dv16  : wd16;
    size_t base = (size_t)(bx < 4096 ? bx : bx - 4096) * 1024;
    size_t i = base + (size_t)tid * 4;
    float4 v = *(const float4*)(in + i);
    ushort4 o; o.x = f2b(v.x); o.y = f2b(v.y); o.z = f2b(v.z); o.w = f2b(v.w);
    *(ushort4*)(outp + i) = o;
  } else if (bx < 7168){
    int b = bx - 5120;
    const float* in      = b < 1024 ? Wv : Wo;
    unsigned short* outp = b < 1024 ? T1 : T2;
    b &= 1023;
    int c0 = (b & 31) * 32, r0 = (b >> 5) * 32;
    int lc = tid & 31, lr = tid >> 5;
    #pragma unroll
    for (int i = 0; i < 4; i++){
      int r = lr + i*8;
      t[r][lc] = f2b(in[(size_t)(r0 + r)*DDIM + c0 + lc]);
    }
    __syncthreads();
    #pragma unroll
    for (int i = 0; i < 4; i++){
      int r = lr + i*8;
      outp[(size_t)(c0 + r)*DDIM + r0 + lc] = t[lc][r];
    }
  } else {
    int b = bx - 7168;                 // 0..15
    int lane = tid & 63, w = tid >> 6;
    int n = b * 64 + lane;
    float acc = 0.f;
    int k0 = w * 256;
    for (int k = k0; k < k0 + 256; k++)
      acc += bv[k] * Wo[(size_t)k*DDIM + n];
    part[w][lane] = acc;
    __syncthreads();
    if (w == 0)
      bc[n] = part[0][lane] + part[1][lane] + part[2][lane] + part[3][lane] + bo[n];
  }
}

// ---------------------------------------------------------------------------
// norm_kernel: blocks [0,4096) = normq (4 tokens each);
//              blocks [4096,5120) = normk (4 doc rows each).
// normk emits dkn (f32 row-major) AND dkn16s (bf16 chunk-major per 32-doc
// tile) so a linear 4KB DMA of one tile yields clean LDS fragments.
// ---------------------------------------------------------------------------
__global__ __launch_bounds__(256)
void norm_kernel(const float* __restrict__ hexw, const float* __restrict__ Wq,
                 float* __restrict__ qn, const float* __restrict__ dkeys,
                 float* __restrict__ dkn, unsigned short* __restrict__ dkn16s){
  __shared__ float Wsh[64*64];
  __shared__ float hx[4][64];
  int bx = blockIdx.x, tid = threadIdx.x;
  int w = tid >> 6, j = tid & 63;
  if (bx < 4096){
    #pragma unroll
    for (int i = 0; i < 16; i++){ int e = tid + i*256; Wsh[e] = Wq[e]; }
    int t = bx * 4 + w;
    hx[w][j] = hexw[(size_t)t*64 + j];
    __syncthreads();
    float s = 0.f;
    #pragma unroll
    for (int h = 0; h < 64; h++) s += hx[w][h] * Wsh[h*64 + j];
    float ss = s*s;
    #pragma unroll
    for (int off = 32; off >= 1; off >>= 1) ss += __shfl_xor(ss, off, 64);
    qn[(size_t)t*64 + j] = s / fmaxf(sqrtf(ss), 1e-12f);
  } else {
    int t = (bx - 4096) * 4 + w;
    float v = dkeys[(size_t)t*64 + j];
    float ss = v*v;
    #pragma unroll
    for (int off = 32; off >= 1; off >>= 1) ss += __shfl_xor(ss, off, 64);
    float o = v / fmaxf(sqrtf(ss), 1e-12f);
    dkn[(size_t)t*64 + j] = o;
    dkn16s[((size_t)(t >> 5) << 11) + ((j >> 3) << 8) + ((t & 31) << 3) + (j & 7)] = f2b(o);
  }
}

// ---------------------------------------------------------------------------
// topk_part (MFMA candidate filter): LDS-dbuf DMA pipeline (R7, verified) +
// cross-g bitonic merge tail (R8, verified) -> per-(token,slice) sorted
// top-8; kbuf = 64 keys/token.
// ---------------------------------------------------------------------------
__global__ __launch_bounds__(256)
void topk_part(const float* __restrict__ qn, const unsigned short* __restrict__ dkn16s,
               unsigned int* __restrict__ kbuf){
  __shared__ __align__(16) unsigned short buf[2][2048];   // 2 x 4KB tiles
  int tid  = threadIdx.x;
  int wv   = tid >> 6;
  int lane = tid & 63;
  int tl   = lane & 15;            // token-in-16 (C col) / doc-in-16 (A row)
  int g    = lane >> 4;            // k-chunk group
  int token = blockIdx.x*64 + wv*16 + tl;
  int dbase = blockIdx.y * SLICE;
  int T0    = dbase >> 5;          // first 32-doc tile of this slice

  // B fragment (token side), converted f32 -> bf16 on the fly (one-time).
  const float* qrow = qn + (size_t)token*64 + g*8;
  float4 u0 = *(const float4*)(qrow);
  float4 u1 = *(const float4*)(qrow + 4);
  float4 v0 = *(const float4*)(qrow + 32);
  float4 v1 = *(const float4*)(qrow + 36);
  short8 q0 = (short8){(short)f2b(u0.x),(short)f2b(u0.y),(short)f2b(u0.z),(short)f2b(u0.w),
                       (short)f2b(u1.x),(short)f2b(u1.y),(short)f2b(u1.z),(short)f2b(u1.w)};
  short8 q1 = (short8){(short)f2b(v0.x),(short)f2b(v0.y),(short)f2b(v0.z),(short)f2b(v0.w),
                       (short)f2b(v1.x),(short)f2b(v1.y),(short)f2b(v1.z),(short)f2b(v1.w)};

  unsigned int keysA[TOPL], keysB[TOPL];
  #pragma unroll
  for (int k = 0; k < TOPL; k++){ keysA[k] = 0u; keysB[k] = 0u; }
  const unsigned int HI = 0xFFFF0000u;
  unsigned int idlow0 = 4095u - (unsigned)(dbase + g*4);

  // prologue: DMA tile 0 into buf[0] (each wave stages its 1KB quarter)
  gld16(dkn16s + ((size_t)T0 << 11) + wv*512 + lane*8, &buf[0][wv*512]);
  __syncthreads();

  #pragma unroll 2
  for (int it = 0; it < SLICE/32; ++it){
    int cur = it & 1;
    if (it < SLICE/32 - 1)
      gld16(dkn16s + ((size_t)(T0 + it + 1) << 11) + wv*512 + lane*8,
            &buf[cur ^ 1][wv*512]);

    const unsigned short* bp = &buf[cur][0];
    short8 a0 = *(const short8*)(bp + g*256        + tl*8);   // docs 0-15, k<32
    short8 a1 = *(const short8*)(bp + (g+4)*256    + tl*8);   // docs 0-15, k>=32
    short8 b0 = *(const short8*)(bp + g*256 + 128  + tl*8);   // docs 16-31, k<32
    short8 b1 = *(const short8*)(bp + (g+4)*256 + 128 + tl*8);// docs 16-31, k>=32

    f32x4 accA = (f32x4){3.0f, 3.0f, 3.0f, 3.0f};
    f32x4 accB = (f32x4){3.0f, 3.0f, 3.0f, 3.0f};
    accA = __builtin_amdgcn_mfma_f32_16x16x32_bf16(a0, q0, accA, 0, 0, 0);
    accB = __builtin_amdgcn_mfma_f32_16x16x32_bf16(b0, q0, accB, 0, 0, 0);
    accA = __builtin_amdgcn_mfma_f32_16x16x32_bf16(a1, q1, accA, 0, 0, 0);
    accB = __builtin_amdgcn_mfma_f32_16x16x32_bf16(b1, q1, accB, 0, 0, 0);

    unsigned int ibA = idlow0 - (unsigned)(it*32);
    unsigned int ibB = ibA - 16u;
    #pragma unroll
    for (int r = 0; r < 4; ++r){
      unsigned int kA = (((__float_as_uint(accA[r]) << 8) - 0xC0000000u) & HI)
                      | (ibA - (unsigned)r);
      unsigned int kB = (((__float_as_uint(accB[r]) << 8) - 0xC0000000u) & HI)
                      | (ibB - (unsigned)r);
      kinsert(keysA, kA);
      kinsert(keysB, kB);
    }
    __syncthreads();   // DMA for next tile done; all reads of cur done
  }

  // merge B into A -> per-lane top-6 of all 128 docs (exact)
  #pragma unroll
  for (int k = 0; k < TOPL; ++k) kinsert(keysA, keysB[k]);

  // ---- cross-g merge: 4 sorted-6 lists -> per-(token,slice) sorted top-8
  unsigned int pb[TOPL], c[8];
  #pragma unroll
  for (int j = 0; j < TOPL; ++j) pb[j] = __shfl_xor(keysA[j], 16, 64);
  c[0] = keysA[0];
  c[1] = keysA[1];
  c[2] = keysA[2] > pb[5] ? keysA[2] : pb[5];
  c[3] = keysA[3] > pb[4] ? keysA[3] : pb[4];
  c[4] = keysA[4] > pb[3] ? keysA[4] : pb[3];
  c[5] = keysA[5] > pb[2] ? keysA[5] : pb[2];
  c[6] = pb[1];
  c[7] = pb[0];
  bitonic8(c);
  unsigned int pc[8], d[8];
  #pragma unroll
  for (int j = 0; j < 8; ++j) pc[j] = __shfl_xor(c[j], 32, 64);
  #pragma unroll
  for (int j = 0; j < 8; ++j) d[j] = c[j] > pc[7-j] ? c[j] : pc[7-j];
  bitonic8(d);

  if (g == 0){
    size_t base = (size_t)token*KPT + (size_t)blockIdx.y*8;
    *(uint4*)&kbuf[base]     = (uint4){d[0], d[1], d[2], d[3]};
    *(uint4*)&kbuf[base + 4] = (uint4){d[4], d[5], d[6], d[7]};
  }
}

// ---------------------------------------------------------------------------
// topk_rescore v2 (R8, verified): wave per token, rank-parallel selection.
// ---------------------------------------------------------------------------
__global__ __launch_bounds__(256)
void topk_rescore(const unsigned int* __restrict__ kbuf, const float* __restrict__ qn,
                  const float* __restrict__ dkn, float* __restrict__ wsm,
                  int* __restrict__ idx){
  __shared__ unsigned int smid[4][16];
  __shared__ float       ssc[4][16];
  int tid = threadIdx.x, wv = tid >> 6, lane = tid & 63;
  int t = blockIdx.x * 4 + wv;

  unsigned int k = kbuf[(size_t)t*KPT + lane];
  int rank = 0;
  #pragma unroll
  for (int i = 0; i < 64; ++i){
    unsigned int o = __shfl(k, i, 64);
    rank += (o > k) ? 1 : 0;
  }
  if (rank < 16) smid[wv][rank] = k;
  __syncthreads();

  // cooperative f32 rescore: candidate cnum = lane>>2, row chunk sub = lane&3
  int cnum = lane >> 2, sub = lane & 3;
  unsigned int mk = smid[wv][cnum];
  int did = 4095 - (int)(mk & 0xFFFFu);
  const float4* kr = (const float4*)(dkn + (size_t)did*64 + sub*16);
  const float4* qp = (const float4*)(qn  + (size_t)t*64   + sub*16);
  float s = 0.f;
  #pragma unroll
  for (int c = 0; c < 4; ++c){
    float4 kv = kr[c], qv = qp[c];
    s += qv.x*kv.x + qv.y*kv.y + qv.z*kv.z + qv.w*kv.w;
  }
  s += __shfl_xor(s, 1, 64);
  s += __shfl_xor(s, 2, 64);
  if (sub == 0) ssc[wv][cnum] = s;
  __syncthreads();

  // exact top-8 of the 16 rescored candidates, rank-parallel on lanes 0..15
  float sc = (lane < 16) ? ssc[wv][lane] : -1e30f;
  int   id = (lane < 16) ? (4095 - (int)(smid[wv][lane] & 0xFFFFu)) : 0x7fffffff;
  int r2 = 0;
  #pragma unroll
  for (int i = 0; i < 16; ++i){
    float os = __shfl(sc, i, 64);
    int   oi = __shfl(id, i, 64);
    r2 += (os > sc || (os == sc && oi < id)) ? 1 : 0;
  }
  float mx = sc;
  #pragma unroll
  for (int off = 1; off < 64; off <<= 1) mx = fmaxf(mx, __shfl_xor(mx, off, 64));
  float e = (lane < 16 && r2 < 8) ? expf(sc - mx) : 0.f;
  float sum = e;
  #pragma unroll
  for (int off = 1; off < 64; off <<= 1) sum += __shfl_xor(sum, off, 64);
  if (lane < 16 && r2 < 8){
    float inv = 1.f / sum;
    wsm[(size_t)t*8 + r2] = e * inv;
    idx[(size_t)t*8 + r2] = id;
  }
}

// ---------------------------------------------------------------------------
// C(M,N) = A(M,K) @ Bt(N,K)^T, bf16 inputs, global_load_lds staging.
// TSTORE: transposed store. PARTIAL: f32 partials at z-offset (split-K).
// 128x128 tile, BK=32, 4 waves, 16x16x32 MFMA.
// ---------------------------------------------------------------------------
template<int TSTORE, int PARTIAL>
__global__ __launch_bounds__(256)
void gemm_bt_kernel(const unsigned short* __restrict__ A, const unsigned short* __restrict__ Bt,
                    void* __restrict__ C, int M, int N, int K){
  __shared__ __align__(16) short As[128*32];
  __shared__ __align__(16) short Bs[128*32];
  int tid  = threadIdx.x;
  int lane = tid & 63;
  int wv   = tid >> 6;
  int wm = wv & 1, wn = wv >> 1;
  size_t bm = (size_t)blockIdx.x * 128, bn = (size_t)blockIdx.y * 128;
  int klen = K / (int)gridDim.z;
  int kz0  = (int)blockIdx.z * klen;

  f32x4 acc[4][4];
  #pragma unroll
  for (int i = 0; i < 4; i++)
    #pragma unroll
    for (int j = 0; j < 4; j++) acc[i][j] = (f32x4){0.f, 0.f, 0.f, 0.f};

  size_t aoff = (bm + (size_t)(tid >> 2))*K + (tid & 3)*8 + kz0;
  size_t boff = (bn + (size_t)(tid >> 2))*K + (tid & 3)*8 + kz0;

  for (int k0 = 0; k0 < klen; k0 += 32){
    __syncthreads();
    gld16(A  + aoff + k0,                 &As[wv*512]);
    gld16(A  + aoff + (size_t)64*K + k0,  &As[2048 + wv*512]);
    gld16(Bt + boff + k0,                 &Bs[wv*512]);
    gld16(Bt + boff + (size_t)64*K + k0,  &Bs[2048 + wv*512]);
    __syncthreads();

    short8 af[4], bf[4];
    int kb = (lane >> 4) * 8;
    int rA = wm*64 + (lane & 15);
    int rB = wn*64 + (lane & 15);
    #pragma unroll
    for (int i = 0; i < 4; i++) af[i] = *(const short8*)&As[(rA + i*16)*32 + kb];
    #pragma unroll
    for (int i = 0; i < 4; i++) bf[i] = *(const short8*)&Bs[(rB + i*16)*32 + kb];
    #pragma unroll
    for (int i = 0; i < 4; i++)
      #pragma unroll
      for (int j = 0; j < 4; j++)
        acc[i][j] = __builtin_amdgcn_mfma_f32_16x16x32_bf16(af[i], bf[j], acc[i][j], 0, 0, 0);
  }

  int ci = lane & 15, rg = lane >> 4;
  #pragma unroll
  for (int i = 0; i < 4; i++)
    #pragma unroll
    for (int j = 0; j < 4; j++)
      #pragma unroll
      for (int r = 0; r < 4; r++){
        size_t row = bm + wm*64 + i*16 + rg*4 + r;
        size_t col = bn + wn*64 + j*16 + ci;
        size_t e = TSTORE ? (col*(size_t)M + row) : (row*(size_t)N + col);
        if (PARTIAL) ((float*)C)[(size_t)blockIdx.z*M*N + e] = acc[i][j][r];
        else         ((unsigned short*)C)[e] = f2b(acc[i][j][r]);
      }
}

// ---------------------------------------------------------------------------
// reduce 4 f32 partials (stride MN20) -> bf16, 4 elems/thread
// ---------------------------------------------------------------------------
__global__ __launch_bounds__(256)
void reduce4_bf16(const float* __restrict__ p, unsigned short* __restrict__ o){
  size_t i = ((size_t)blockIdx.x * 256 + threadIdx.x) * 4;
  float4 a0 = *(const float4*)(p + i);
  float4 a1 = *(const float4*)(p + i + (size_t)MN20);
  float4 a2 = *(const float4*)(p + i + (size_t)2*MN20);
  float4 a3 = *(const float4*)(p + i + (size_t)3*MN20);
  ushort4 r;
  r.x = f2b(a0.x + a1.x + a2.x + a3.x);
  r.y = f2b(a0.y + a1.y + a2.y + a3.y);
  r.z = f2b(a0.z + a1.z + a2.z + a3.z);
  r.w = f2b(a0.w + a1.w + a2.w + a3.w);
  *(ushort4*)(o + i) = r;
}

// ---------------------------------------------------------------------------
// out[t][c] = x[t][c] + g*(sum_k w[t,k]*P[idx[t,k]][c] + bc[c])   (f32 I/O)
// v2: 2 tokens/block (128 threads x 8 channels each), short8 P gathers
// (16B/lane), non-temporal x loads / out stores so the streamed 128 MB does
// not evict the L2-resident P (8 MB) between gathers (R8: 40 MB P re-fetch).
// ---------------------------------------------------------------------------
__global__ __launch_bounds__(256)
void output_kernel(const float* __restrict__ x, const float* __restrict__ wsm,
                   const int* __restrict__ idx, const unsigned short* __restrict__ P,
                   const float* __restrict__ bc, const float* __restrict__ gate,
                   float* __restrict__ out){
  __shared__ float ws8[2][8]; __shared__ int is8[2][8];
  int tid = threadIdx.x;
  int t0 = blockIdx.x * 2;
  if (tid < 16){
    int tt = tid >> 3, kk = tid & 7;
    ws8[tt][kk] = wsm[(size_t)(t0 + tt)*8 + kk];
    int ii = idx[(size_t)(t0 + tt)*8 + kk];
    is8[tt][kk] = ii < 0 ? 0 : (ii > NDOCS-1 ? NDOCS-1 : ii);
  }
  __syncthreads();
  float g = 1.f / (1.f + expf(-gate[0]));
  int tt = tid >> 7;               // token within block (0/1)
  int t  = t0 + tt;
  int c  = (tid & 127) * 8;        // 8 channels per thread
  float a[8] = {0.f,0.f,0.f,0.f,0.f,0.f,0.f,0.f};
  #pragma unroll
  for (int k = 0; k < 8; k++){
    short8 u = *(const short8*)(P + (size_t)is8[tt][k]*DDIM + c);
    float w = ws8[tt][k];
    #pragma unroll
    for (int j = 0; j < 8; j++) a[j] += w * b2f((unsigned short)u[j]);
  }
  const f32x4* xp = (const f32x4*)(x + (size_t)t*DDIM + c);
  f32x4 xf0 = __builtin_nontemporal_load(xp);
  f32x4 xf1 = __builtin_nontemporal_load(xp + 1);
  const f32x4* bp = (const f32x4*)(bc + c);
  f32x4 b0 = bp[0], b1 = bp[1];
  f32x4 o0, o1;
  #pragma unroll
  for (int j = 0; j < 4; j++){
    o0[j] = xf0[j] + g * (a[j]     + b0[j]);
    o1[j] = xf1[j] + g * (a[j + 4] + b1[j]);
  }
  f32x4* op = (f32x4*)(out + (size_t)t*DDIM + c);
  __builtin_nontemporal_store(o0, op);
  __builtin_nontemporal_store(o1, op + 1);
}

// Fallback: "ws too small" signature (absmax == ref max, no fault)
__global__ __launch_bounds__(256)
void zero_out_kernel(float* __restrict__ out){
  size_t i = ((size_t)blockIdx.x * 256 + threadIdx.x) * 4;
  *(float4*)(out + i) = (float4){0.f,0.f,0.f,0.f};
}

// ---------------------------------------------------------------------------
extern "C" void kernel_launch(void* const* d_in, const int* in_sizes, int n_in,
                              void* d_out, int out_size, void* d_ws, size_t ws_size,
                              hipStream_t stream){
  (void)in_sizes; (void)n_in; (void)out_size;
  const float* x     = (const float*)d_in[0];
  const float* hexw  = (const float*)d_in[1];
  const float* dkeys = (const float*)d_in[2];
  const float* dvals = (const float*)d_in[3];
  const float* Wqh   = (const float*)d_in[4];
  // d_in[5]=Wq, d_in[6]=Wk, d_in[8]=bq, d_in[9]=bk: dead (degenerate attention)
  const float* Wv    = (const float*)d_in[7];
  const float* bv    = (const float*)d_in[10];
  const float* Wo    = (const float*)d_in[11];
  const float* bo    = (const float*)d_in[12];
  const float* Wdoc  = (const float*)d_in[13];
  const float* gate  = (const float*)d_in[14];
  float* out = (float*)d_out;

  const size_t NEED = ((size_t)22 << 20) + 4096;
  if (ws_size < NEED){
    zero_out_kernel<<<NTOK*DDIM/1024, 256, 0, stream>>>(out);
    return;
  }

  // Workspace layout (lifetime-overlapped), 22 MB + 4 KB:
  //  [0,4) qn  [4,5) dkn  [5,5.5) wsm  [5.5,6) idx
  //  [6,8) T1  [8,10) T2  [10,12) tmp
  //  [12,14) WcT -> dead after G3; dkn16s (512 KB) after G3
  //  [14,22) P (bf16, live to end)   [22M,+4K) bc
  // d_out (64 MiB) doubles as scratch before output_kernel overwrites it:
  //  [0,16) split-K4 f32 partials (G1/G2), then kbuf keys [0,4) for topk
  //  [16,24) dvals bf16   [24,26) Wdoc bf16
  char* ws = (char*)d_ws;
  float* qn             = (float*)(ws);
  float* dkn            = (float*)(ws + ((size_t)4 << 20));
  float* wsm            = (float*)(ws + ((size_t)5 << 20));
  int*   idx            = (int*)  (ws + ((size_t)5 << 20) + (512 << 10));
  unsigned short* T1    = (unsigned short*)(ws + ((size_t)6  << 20));
  unsigned short* T2    = (unsigned short*)(ws + ((size_t)8  << 20));
  unsigned short* tmp   = (unsigned short*)(ws + ((size_t)10 << 20));
  unsigned short* WcT   = (unsigned short*)(ws + ((size_t)12 << 20));
  unsigned short* P     = (unsigned short*)(ws + ((size_t)14 << 20));
  unsigned short* dkn16s= (unsigned short*)(ws + ((size_t)12 << 20));  // after G3
  float* bc             = (float*)(ws + ((size_t)22 << 20));
  char* dob             = (char*)d_out;
  float*          pbuf = (float*)dob;                                  // 16 MB
  unsigned int*   kbuf = (unsigned int*)dob;                           // 4 MB (later)
  unsigned short* dv16 = (unsigned short*)(dob + ((size_t)16 << 20));  // 8 MB
  unsigned short* wd16 = (unsigned short*)(dob + ((size_t)24 << 20));  // 2 MB

  // Phase 1: P = dvals @ (W_doc@Wv@Wo); bc = bv@Wo + bo.
  prep_kernel<<<7184, 256, 0, stream>>>(dvals, dv16, Wdoc, wd16, Wv, T1, Wo, T2,
                                        bv, bo, bc);
  gemm_bt_kernel<0,1><<<dim3(8,8,4),  256, 0, stream>>>(wd16, T1, pbuf, DDIM, DDIM, DDIM);
  reduce4_bf16<<<1024, 256, 0, stream>>>(pbuf, tmp);
  gemm_bt_kernel<1,1><<<dim3(8,8,4),  256, 0, stream>>>(tmp,  T2, pbuf, DDIM, DDIM, DDIM);
  reduce4_bf16<<<1024, 256, 0, stream>>>(pbuf, WcT);
  gemm_bt_kernel<0,0><<<dim3(32,8,1), 256, 0, stream>>>(dv16, WcT, P, NDOCS, DDIM, DDIM);

  // Phase 2: retrieval — MFMA bf16 candidate filter + key-ranked f32 rescore.
  norm_kernel<<<4096 + NDOCS/4, 256, 0, stream>>>(hexw, Wqh, qn, dkeys, dkn, dkn16s);
  topk_part<<<dim3(NTOK/64, NSLICE), 256, 0, stream>>>(qn, dkn16s, kbuf);
  topk_rescore<<<NTOK/4, 256, 0, stream>>>(kbuf, qn, dkn, wsm, idx);

  // out = x + sigmoid(gate) * (gather-combine(P) + bc)
  output_kernel<<<NTOK/2, 256, 0, stream>>>(x, wsm, idx, P, bc, gate, out);
}

// Round 11
// 303.275 us; speedup vs baseline: 1.1004x; 1.1004x over previous
//
#include <hip/hip_runtime.h>
#include <math.h>

// Problem constants (inputs/outputs are f32; verified round 4)
#define NTOK  16384   // B*T
#define DDIM  1024
#define NDOCS 4096
#define NSLICE 8            // doc slices for topk_part
#define SLICE (NDOCS/NSLICE)  // 512 docs per slice
#define TOPL  6             // per-lane candidate list length
#define KPT   64            // candidate keys per token (8 slices x top-8)
#define MN20  (1u<<20)      // 1024*1024

typedef __attribute__((ext_vector_type(8))) short short8;
typedef __attribute__((ext_vector_type(4))) float f32x4;

__device__ __forceinline__ float b2f(unsigned short u){
  union { unsigned int i; float f; } v; v.i = ((unsigned int)u) << 16; return v.f;
}
__device__ __forceinline__ unsigned short f2b(float f){
  union { float f; unsigned int i; } v; v.f = f;
  unsigned int r = v.i + 0x7fffu + ((v.i >> 16) & 1u);   // RNE
  return (unsigned short)(r >> 16);
}
// async global->LDS, 16B per lane: LDS dest = wave-uniform base + lane*16
__device__ __forceinline__ void gld16(const void* g, void* l){
  __builtin_amdgcn_global_load_lds(
      (const __attribute__((address_space(1))) void*)g,
      (__attribute__((address_space(3))) void*)l, 16, 0, 0);
}
// sorted-desc top-TOPL insert: keys[k] = median(keys[k-1], keys[k], key).
__device__ __forceinline__ void kinsert(unsigned int* keys, unsigned int key){
  #pragma unroll
  for (int k = TOPL-1; k >= 1; --k){
    unsigned int lo = keys[k-1] < key ? keys[k-1] : key;
    keys[k] = keys[k] > lo ? keys[k] : lo;
  }
  keys[0] = keys[0] > key ? keys[0] : key;
}
__device__ __forceinline__ void ceswap(unsigned int& a, unsigned int& b){
  unsigned int mx = a > b ? a : b, mn = a > b ? b : a; a = mx; b = mn;
}
// sort a bitonic 8-sequence descending (3 half-cleaner stages, 12 CE)
__device__ __forceinline__ void bitonic8(unsigned int* c){
  ceswap(c[0],c[4]); ceswap(c[1],c[5]); ceswap(c[2],c[6]); ceswap(c[3],c[7]);
  ceswap(c[0],c[2]); ceswap(c[1],c[3]); ceswap(c[4],c[6]); ceswap(c[5],c[7]);
  ceswap(c[0],c[1]); ceswap(c[2],c[3]); ceswap(c[4],c[5]); ceswap(c[6],c[7]);
}

// ---------------------------------------------------------------------------
// GEMM body: C(M,N) = A(M,K) @ Bt(N,K)^T, bf16 in, global_load_lds staging.
// PARTIAL: f32 partials at zoff elems; else bf16. 128x128 tile, BK=32,
// 4 waves, 16x16x32 MFMA. As/Bs: 4096 shorts each (8KB+8KB).
// R10 post-mortem: staging offsets MUST be wv*512 / 2048+wv*512 — each
// wave's gld16 covers 512 shorts (64 lanes x 16B). R10's wv*256 overlapped
// waves and left half of As/Bs unwritten -> NaN. Fixed (matches R9 verified).
// ---------------------------------------------------------------------------
template<int PARTIAL>
__device__ __forceinline__ void gemm_body(
    const unsigned short* __restrict__ A, const unsigned short* __restrict__ Bt,
    void* __restrict__ C, int M, int N, int K, int klen, int kz0, size_t zoff,
    int bxg, int byg, short* As, short* Bs){
  int tid  = threadIdx.x;
  int lane = tid & 63;
  int wv   = tid >> 6;
  int wm = wv & 1, wn = wv >> 1;
  size_t bm = (size_t)bxg * 128, bn = (size_t)byg * 128;

  f32x4 acc[4][4];
  #pragma unroll
  for (int i = 0; i < 4; i++)
    #pragma unroll
    for (int j = 0; j < 4; j++) acc[i][j] = (f32x4){0.f, 0.f, 0.f, 0.f};

  size_t aoff = (bm + (size_t)(tid >> 2))*K + (tid & 3)*8 + kz0;
  size_t boff = (bn + (size_t)(tid >> 2))*K + (tid & 3)*8 + kz0;

  for (int k0 = 0; k0 < klen; k0 += 32){
    __syncthreads();
    gld16(A  + aoff + k0,                 &As[wv*512]);
    gld16(A  + aoff + (size_t)64*K + k0,  &As[2048 + wv*512]);
    gld16(Bt + boff + k0,                 &Bs[wv*512]);
    gld16(Bt + boff + (size_t)64*K + k0,  &Bs[2048 + wv*512]);
    __syncthreads();

    short8 af[4], bf[4];
    int kb = (lane >> 4) * 8;
    int rA = wm*64 + (lane & 15);
    int rB = wn*64 + (lane & 15);
    #pragma unroll
    for (int i = 0; i < 4; i++) af[i] = *(const short8*)&As[(rA + i*16)*32 + kb];
    #pragma unroll
    for (int i = 0; i < 4; i++) bf[i] = *(const short8*)&Bs[(rB + i*16)*32 + kb];
    #pragma unroll
    for (int i = 0; i < 4; i++)
      #pragma unroll
      for (int j = 0; j < 4; j++)
        acc[i][j] = __builtin_amdgcn_mfma_f32_16x16x32_bf16(af[i], bf[j], acc[i][j], 0, 0, 0);
  }

  int ci = lane & 15, rg = lane >> 4;
  #pragma unroll
  for (int i = 0; i < 4; i++)
    #pragma unroll
    for (int j = 0; j < 4; j++)
      #pragma unroll
      for (int r = 0; r < 4; r++){
        size_t row = bm + wm*64 + i*16 + rg*4 + r;
        size_t col = bn + wn*64 + j*16 + ci;
        size_t e = row*(size_t)N + col;
        if (PARTIAL) ((float*)C)[zoff + e] = acc[i][j][r];
        else         ((unsigned short*)C)[e] = f2b(acc[i][j][r]);
      }
}

// ---------------------------------------------------------------------------
// topk_part body (MFMA candidate filter; R7/R8 verified): LDS-dbuf DMA
// pipeline + cross-g bitonic merge -> per-(token,slice) sorted top-8.
// buf: 2048 ushorts x 2 tiles (8KB).
// ---------------------------------------------------------------------------
__device__ __forceinline__ void part_body(
    int px, int py, const float* __restrict__ qn,
    const unsigned short* __restrict__ dkn16s, unsigned int* __restrict__ kbuf,
    unsigned short* buf){
  int tid  = threadIdx.x;
  int wv   = tid >> 6;
  int lane = tid & 63;
  int tl   = lane & 15;
  int g    = lane >> 4;
  int token = px*64 + wv*16 + tl;
  int dbase = py * SLICE;
  int T0    = dbase >> 5;

  const float* qrow = qn + (size_t)token*64 + g*8;
  float4 u0 = *(const float4*)(qrow);
  float4 u1 = *(const float4*)(qrow + 4);
  float4 v0 = *(const float4*)(qrow + 32);
  float4 v1 = *(const float4*)(qrow + 36);
  short8 q0 = (short8){(short)f2b(u0.x),(short)f2b(u0.y),(short)f2b(u0.z),(short)f2b(u0.w),
                       (short)f2b(u1.x),(short)f2b(u1.y),(short)f2b(u1.z),(short)f2b(u1.w)};
  short8 q1 = (short8){(short)f2b(v0.x),(short)f2b(v0.y),(short)f2b(v0.z),(short)f2b(v0.w),
                       (short)f2b(v1.x),(short)f2b(v1.y),(short)f2b(v1.z),(short)f2b(v1.w)};

  unsigned int keysA[TOPL], keysB[TOPL];
  #pragma unroll
  for (int k = 0; k < TOPL; k++){ keysA[k] = 0u; keysB[k] = 0u; }
  const unsigned int HI = 0xFFFF0000u;
  unsigned int idlow0 = 4095u - (unsigned)(dbase + g*4);

  gld16(dkn16s + ((size_t)T0 << 11) + wv*512 + lane*8, &buf[wv*512]);
  __syncthreads();

  #pragma unroll 2
  for (int it = 0; it < SLICE/32; ++it){
    int cur = it & 1;
    if (it < SLICE/32 - 1)
      gld16(dkn16s + ((size_t)(T0 + it + 1) << 11) + wv*512 + lane*8,
            &buf[(cur ^ 1)*2048 + wv*512]);

    const unsigned short* bp = &buf[cur*2048];
    short8 a0 = *(const short8*)(bp + g*256        + tl*8);
    short8 a1 = *(const short8*)(bp + (g+4)*256    + tl*8);
    short8 b0 = *(const short8*)(bp + g*256 + 128  + tl*8);
    short8 b1 = *(const short8*)(bp + (g+4)*256 + 128 + tl*8);

    f32x4 accA = (f32x4){3.0f, 3.0f, 3.0f, 3.0f};
    f32x4 accB = (f32x4){3.0f, 3.0f, 3.0f, 3.0f};
    accA = __builtin_amdgcn_mfma_f32_16x16x32_bf16(a0, q0, accA, 0, 0, 0);
    accB = __builtin_amdgcn_mfma_f32_16x16x32_bf16(b0, q0, accB, 0, 0, 0);
    accA = __builtin_amdgcn_mfma_f32_16x16x32_bf16(a1, q1, accA, 0, 0, 0);
    accB = __builtin_amdgcn_mfma_f32_16x16x32_bf16(b1, q1, accB, 0, 0, 0);

    unsigned int ibA = idlow0 - (unsigned)(it*32);
    unsigned int ibB = ibA - 16u;
    #pragma unroll
    for (int r = 0; r < 4; ++r){
      unsigned int kA = (((__float_as_uint(accA[r]) << 8) - 0xC0000000u) & HI)
                      | (ibA - (unsigned)r);
      unsigned int kB = (((__float_as_uint(accB[r]) << 8) - 0xC0000000u) & HI)
                      | (ibB - (unsigned)r);
      kinsert(keysA, kA);
      kinsert(keysB, kB);
    }
    __syncthreads();
  }

  #pragma unroll
  for (int k = 0; k < TOPL; ++k) kinsert(keysA, keysB[k]);

  unsigned int pb[TOPL], c[8];
  #pragma unroll
  for (int j = 0; j < TOPL; ++j) pb[j] = __shfl_xor(keysA[j], 16, 64);
  c[0] = keysA[0];
  c[1] = keysA[1];
  c[2] = keysA[2] > pb[5] ? keysA[2] : pb[5];
  c[3] = keysA[3] > pb[4] ? keysA[3] : pb[4];
  c[4] = keysA[4] > pb[3] ? keysA[4] : pb[3];
  c[5] = keysA[5] > pb[2] ? keysA[5] : pb[2];
  c[6] = pb[1];
  c[7] = pb[0];
  bitonic8(c);
  unsigned int pc[8], d[8];
  #pragma unroll
  for (int j = 0; j < 8; ++j) pc[j] = __shfl_xor(c[j], 32, 64);
  #pragma unroll
  for (int j = 0; j < 8; ++j) d[j] = c[j] > pc[7-j] ? c[j] : pc[7-j];
  bitonic8(d);

  if (g == 0){
    size_t base = (size_t)token*KPT + (size_t)py*8;
    *(uint4*)&kbuf[base]     = (uint4){d[0], d[1], d[2], d[3]};
    *(uint4*)&kbuf[base + 4] = (uint4){d[4], d[5], d[6], d[7]};
  }
}

// ---------------------------------------------------------------------------
// rescore body (R8 verified): wave per token, rank-parallel selection.
// smid: 64 u32, ssc: 64 f32 (LDS carve).
// ---------------------------------------------------------------------------
__device__ __forceinline__ void rescore_body(
    int b2, const unsigned int* __restrict__ kbuf, const float* __restrict__ qn,
    const float* __restrict__ dkn, float* __restrict__ wsm, int* __restrict__ idx,
    unsigned int* smid, float* ssc){
  int tid = threadIdx.x, wv = tid >> 6, lane = tid & 63;
  int t = b2 * 4 + wv;

  unsigned int k = kbuf[(size_t)t*KPT + lane];
  int rank = 0;
  #pragma unroll
  for (int i = 0; i < 64; ++i){
    unsigned int o = __shfl(k, i, 64);
    rank += (o > k) ? 1 : 0;
  }
  if (rank < 16) smid[wv*16 + rank] = k;
  __syncthreads();

  int cnum = lane >> 2, sub = lane & 3;
  unsigned int mk = smid[wv*16 + cnum];
  int did = 4095 - (int)(mk & 0xFFFFu);
  const float4* kr = (const float4*)(dkn + (size_t)did*64 + sub*16);
  const float4* qp = (const float4*)(qn  + (size_t)t*64   + sub*16);
  float s = 0.f;
  #pragma unroll
  for (int c = 0; c < 4; ++c){
    float4 kv = kr[c], qv = qp[c];
    s += qv.x*kv.x + qv.y*kv.y + qv.z*kv.z + qv.w*kv.w;
  }
  s += __shfl_xor(s, 1, 64);
  s += __shfl_xor(s, 2, 64);
  if (sub == 0) ssc[wv*16 + cnum] = s;
  __syncthreads();

  float sc = (lane < 16) ? ssc[wv*16 + lane] : -1e30f;
  int   id = (lane < 16) ? (4095 - (int)(smid[wv*16 + lane] & 0xFFFFu)) : 0x7fffffff;
  int r2 = 0;
  #pragma unroll
  for (int i = 0; i < 16; ++i){
    float os = __shfl(sc, i, 64);
    int   oi = __shfl(id, i, 64);
    r2 += (os > sc || (os == sc && oi < id)) ? 1 : 0;
  }
  float mx = sc;
  #pragma unroll
  for (int off = 1; off < 64; off <<= 1) mx = fmaxf(mx, __shfl_xor(mx, off, 64));
  float e = (lane < 16 && r2 < 8) ? expf(sc - mx) : 0.f;
  float sum = e;
  #pragma unroll
  for (int off = 1; off < 64; off <<= 1) sum += __shfl_xor(sum, off, 64);
  if (lane < 16 && r2 < 8){
    float inv = 1.f / sum;
    wsm[(size_t)t*8 + r2] = e * inv;
    idx[(size_t)t*8 + r2] = id;
  }
}

// ---------------------------------------------------------------------------
// L1: prep + norm fused (all independent preprocessing, block ranges):
//  [0,4096) cast dvals->dv16; [4096,5120) cast Wdoc->wd16;
//  [5120,6144) transpose Wv->T1; [6144,7168) transpose Wo->T2;
//  [7168,7184) bc = bv@Wo + bo;
//  [7184,11280) normq (4 tokens each); [11280,12304) normk (4 rows each)
// ---------------------------------------------------------------------------
__global__ __launch_bounds__(256)
void prep_norm_kernel(const float* __restrict__ dvals, unsigned short* __restrict__ dv16,
                 const float* __restrict__ Wdoc,  unsigned short* __restrict__ wd16,
                 const float* __restrict__ Wv,    unsigned short* __restrict__ T1,
                 const float* __restrict__ Wo,    unsigned short* __restrict__ T2,
                 const float* __restrict__ bv, const float* __restrict__ bo,
                 float* __restrict__ bc,
                 const float* __restrict__ hexw, const float* __restrict__ Wq,
                 float* __restrict__ qn, const float* __restrict__ dkeys,
                 float* __restrict__ dkn, unsigned short* __restrict__ dkn16s){
  __shared__ unsigned short t[32][33];
  __shared__ float part[4][64];
  __shared__ float Wsh[64*64];
  __shared__ float hx[4][64];
  int bx = blockIdx.x, tid = threadIdx.x;
  if (bx < 5120){
    const float* in        = bx < 4096 ? dvals : Wdoc;
    unsigned short* outp   = bx < 4096 ? dv16  : wd16;
    size_t base = (size_t)(bx < 4096 ? bx : bx - 4096) * 1024;
    size_t i = base + (size_t)tid * 4;
    float4 v = *(const float4*)(in + i);
    ushort4 o; o.x = f2b(v.x); o.y = f2b(v.y); o.z = f2b(v.z); o.w = f2b(v.w);
    *(ushort4*)(outp + i) = o;
  } else if (bx < 7168){
    int b = bx - 5120;
    const float* in      = b < 1024 ? Wv : Wo;
    unsigned short* outp = b < 1024 ? T1 : T2;
    b &= 1023;
    int c0 = (b & 31) * 32, r0 = (b >> 5) * 32;
    int lc = tid & 31, lr = tid >> 5;
    #pragma unroll
    for (int i = 0; i < 4; i++){
      int r = lr + i*8;
      t[r][lc] = f2b(in[(size_t)(r0 + r)*DDIM + c0 + lc]);
    }
    __syncthreads();
    #pragma unroll
    for (int i = 0; i < 4; i++){
      int r = lr + i*8;
      outp[(size_t)(c0 + r)*DDIM + r0 + lc] = t[lc][r];
    }
  } else if (bx < 7184){
    int b = bx - 7168;                 // 0..15
    int lane = tid & 63, w = tid >> 6;
    int n = b * 64 + lane;
    float acc = 0.f;
    int k0 = w * 256;
    for (int k = k0; k < k0 + 256; k++)
      acc += bv[k] * Wo[(size_t)k*DDIM + n];
    part[w][lane] = acc;
    __syncthreads();
    if (w == 0)
      bc[n] = part[0][lane] + part[1][lane] + part[2][lane] + part[3][lane] + bo[n];
  } else if (bx < 11280){
    int b = bx - 7184;
    int w = tid >> 6, j = tid & 63;
    #pragma unroll
    for (int i = 0; i < 16; i++){ int e = tid + i*256; Wsh[e] = Wq[e]; }
    int tt = b * 4 + w;
    hx[w][j] = hexw[(size_t)tt*64 + j];
    __syncthreads();
    float s = 0.f;
    #pragma unroll
    for (int h = 0; h < 64; h++) s += hx[w][h] * Wsh[h*64 + j];
    float ss = s*s;
    #pragma unroll
    for (int off = 32; off >= 1; off >>= 1) ss += __shfl_xor(ss, off, 64);
    qn[(size_t)tt*64 + j] = s / fmaxf(sqrtf(ss), 1e-12f);
  } else {
    int b = bx - 11280;
    int w = tid >> 6, j = tid & 63;
    int tt = b * 4 + w;
    float v = dkeys[(size_t)tt*64 + j];
    float ss = v*v;
    #pragma unroll
    for (int off = 32; off >= 1; off >>= 1) ss += __shfl_xor(ss, off, 64);
    float o = v / fmaxf(sqrtf(ss), 1e-12f);
    dkn[(size_t)tt*64 + j] = o;
    dkn16s[((size_t)(tt >> 5) << 11) + ((j >> 3) << 8) + ((tt & 31) << 3) + (j & 7)] = f2b(o);
  }
}

// ---------------------------------------------------------------------------
// L2: G1 (256 blocks, split-K4, f32 partials) + topk_part (2048 blocks).
// Both depend only on L1. G1 blocks first (1/CU); part fills remaining slots.
// ---------------------------------------------------------------------------
__global__ __launch_bounds__(256)
void g1_part_kernel(const unsigned short* __restrict__ A, const unsigned short* __restrict__ Bt,
                    float* __restrict__ pbuf, const float* __restrict__ qn,
                    const unsigned short* __restrict__ dkn16s, unsigned int* __restrict__ kbuf){
  __shared__ __align__(16) short lds[8192];   // 16KB: GEMM As|Bs; part buf
  int b = blockIdx.x;
  if (b < 256){
    int bz = b >> 6, rem = b & 63;
    gemm_body<1>(A, Bt, pbuf, DDIM, DDIM, DDIM, 256, bz*256, (size_t)bz*MN20,
                 rem & 7, rem >> 3, lds, lds + 4096);
  } else {
    int b2 = b - 256;
    part_body(b2 & 255, b2 >> 8, qn, dkn16s, kbuf, (unsigned short*)lds);
  }
}

// ---------------------------------------------------------------------------
// L4: G2 standalone (split-K4, transposed f32-partial store).
// Staging offsets wv*512 / 2048+wv*512 (R10 bugfix, matches R9 verified).
// ---------------------------------------------------------------------------
__global__ __launch_bounds__(256)
void g2_kernel(const unsigned short* __restrict__ A, const unsigned short* __restrict__ Bt,
               float* __restrict__ C){
  __shared__ __align__(16) short lds[8192];
  int b = blockIdx.x;
  int bz = b >> 6, rem = b & 63;
  int bxg = rem & 7, byg = rem >> 3;
  short* As = lds; short* Bs = lds + 4096;
  int tid = threadIdx.x, lane = tid & 63, wv = tid >> 6;
  int wm = wv & 1, wn = wv >> 1;
  size_t bm = (size_t)bxg * 128, bn = (size_t)byg * 128;
  int K = DDIM, klen = 256, kz0 = bz * 256;
  f32x4 acc[4][4];
  #pragma unroll
  for (int i = 0; i < 4; i++)
    #pragma unroll
    for (int j = 0; j < 4; j++) acc[i][j] = (f32x4){0.f,0.f,0.f,0.f};
  size_t aoff = (bm + (size_t)(tid >> 2))*K + (tid & 3)*8 + kz0;
  size_t boff = (bn + (size_t)(tid >> 2))*K + (tid & 3)*8 + kz0;
  for (int k0 = 0; k0 < klen; k0 += 32){
    __syncthreads();
    gld16(A  + aoff + k0,                 &As[wv*512]);
    gld16(A  + aoff + (size_t)64*K + k0,  &As[2048 + wv*512]);
    gld16(Bt + boff + k0,                 &Bs[wv*512]);
    gld16(Bt + boff + (size_t)64*K + k0,  &Bs[2048 + wv*512]);
    __syncthreads();
    short8 af[4], bf[4];
    int kb = (lane >> 4) * 8;
    int rA = wm*64 + (lane & 15);
    int rB = wn*64 + (lane & 15);
    #pragma unroll
    for (int i = 0; i < 4; i++) af[i] = *(const short8*)&As[(rA + i*16)*32 + kb];
    #pragma unroll
    for (int i = 0; i < 4; i++) bf[i] = *(const short8*)&Bs[(rB + i*16)*32 + kb];
    #pragma unroll
    for (int i = 0; i < 4; i++)
      #pragma unroll
      for (int j = 0; j < 4; j++)
        acc[i][j] = __builtin_amdgcn_mfma_f32_16x16x32_bf16(af[i], bf[j], acc[i][j], 0, 0, 0);
  }
  int ci = lane & 15, rg = lane >> 4;
  #pragma unroll
  for (int i = 0; i < 4; i++)
    #pragma unroll
    for (int j = 0; j < 4; j++)
      #pragma unroll
      for (int r = 0; r < 4; r++){
        size_t row = bm + wm*64 + i*16 + rg*4 + r;
        size_t col = bn + wn*64 + j*16 + ci;
        C[(size_t)bz*MN20 + col*(size_t)DDIM + row] = acc[i][j][r];  // transposed
      }
}

// ---------------------------------------------------------------------------
// L6: G3 (256 blocks, 4096x1024x1024 bf16 direct) + rescore (4096 blocks).
// G3 needs WcT (L5); rescore needs kbuf (L2). G3 blocks first.
// ---------------------------------------------------------------------------
__global__ __launch_bounds__(256)
void g3_rescore_kernel(const unsigned short* __restrict__ dv16,
                       const unsigned short* __restrict__ WcT,
                       unsigned short* __restrict__ P,
                       const unsigned int* __restrict__ kbuf,
                       const float* __restrict__ qn, const float* __restrict__ dkn,
                       float* __restrict__ wsm, int* __restrict__ idx){
  __shared__ __align__(16) short lds[8192];
  int b = blockIdx.x;
  if (b < 256){
    gemm_body<0>(dv16, WcT, P, NDOCS, DDIM, DDIM, DDIM, 0, 0,
                 b & 31, b >> 5, lds, lds + 4096);
  } else {
    rescore_body(b - 256, kbuf, qn, dkn, wsm, idx,
                 (unsigned int*)lds, (float*)((char*)lds + 256));
  }
}

// ---------------------------------------------------------------------------
// reduce 4 f32 partials (stride MN20) -> bf16, 4 elems/thread
// ---------------------------------------------------------------------------
__global__ __launch_bounds__(256)
void reduce4_bf16(const float* __restrict__ p, unsigned short* __restrict__ o){
  size_t i = ((size_t)blockIdx.x * 256 + threadIdx.x) * 4;
  float4 a0 = *(const float4*)(p + i);
  float4 a1 = *(const float4*)(p + i + (size_t)MN20);
  float4 a2 = *(const float4*)(p + i + (size_t)2*MN20);
  float4 a3 = *(const float4*)(p + i + (size_t)3*MN20);
  ushort4 r;
  r.x = f2b(a0.x + a1.x + a2.x + a3.x);
  r.y = f2b(a0.y + a1.y + a2.y + a3.y);
  r.z = f2b(a0.z + a1.z + a2.z + a3.z);
  r.w = f2b(a0.w + a1.w + a2.w + a3.w);
  *(ushort4*)(o + i) = r;
}

// ---------------------------------------------------------------------------
// out[t][c] = x[t][c] + g*(sum_k w[t,k]*P[idx[t,k]][c] + bc[c])   (f32 I/O)
// 2 tokens/block, short8 P gathers (16B/lane). nt hints reverted (R9).
// ---------------------------------------------------------------------------
__global__ __launch_bounds__(256)
void output_kernel(const float* __restrict__ x, const float* __restrict__ wsm,
                   const int* __restrict__ idx, const unsigned short* __restrict__ P,
                   const float* __restrict__ bc, const float* __restrict__ gate,
                   float* __restrict__ out){
  __shared__ float ws8[2][8]; __shared__ int is8[2][8];
  int tid = threadIdx.x;
  int t0 = blockIdx.x * 2;
  if (tid < 16){
    int tt = tid >> 3, kk = tid & 7;
    ws8[tt][kk] = wsm[(size_t)(t0 + tt)*8 + kk];
    int ii = idx[(size_t)(t0 + tt)*8 + kk];
    is8[tt][kk] = ii < 0 ? 0 : (ii > NDOCS-1 ? NDOCS-1 : ii);
  }
  __syncthreads();
  float g = 1.f / (1.f + expf(-gate[0]));
  int tt = tid >> 7;               // token within block (0/1)
  int t  = t0 + tt;
  int c  = (tid & 127) * 8;        // 8 channels per thread
  float a[8] = {0.f,0.f,0.f,0.f,0.f,0.f,0.f,0.f};
  #pragma unroll
  for (int k = 0; k < 8; k++){
    short8 u = *(const short8*)(P + (size_t)is8[tt][k]*DDIM + c);
    float w = ws8[tt][k];
    #pragma unroll
    for (int j = 0; j < 8; j++) a[j] += w * b2f((unsigned short)u[j]);
  }
  const f32x4* xp = (const f32x4*)(x + (size_t)t*DDIM + c);
  f32x4 xf0 = xp[0];
  f32x4 xf1 = xp[1];
  const f32x4* bp = (const f32x4*)(bc + c);
  f32x4 b0 = bp[0], b1 = bp[1];
  f32x4 o0, o1;
  #pragma unroll
  for (int j = 0; j < 4; j++){
    o0[j] = xf0[j] + g * (a[j]     + b0[j]);
    o1[j] = xf1[j] + g * (a[j + 4] + b1[j]);
  }
  f32x4* op = (f32x4*)(out + (size_t)t*DDIM + c);
  op[0] = o0;
  op[1] = o1;
}

// Fallback: "ws too small" signature (absmax == ref max, no fault)
__global__ __launch_bounds__(256)
void zero_out_kernel(float* __restrict__ out){
  size_t i = ((size_t)blockIdx.x * 256 + threadIdx.x) * 4;
  *(float4*)(out + i) = (float4){0.f,0.f,0.f,0.f};
}

// ---------------------------------------------------------------------------
extern "C" void kernel_launch(void* const* d_in, const int* in_sizes, int n_in,
                              void* d_out, int out_size, void* d_ws, size_t ws_size,
                              hipStream_t stream){
  (void)in_sizes; (void)n_in; (void)out_size;
  const float* x     = (const float*)d_in[0];
  const float* hexw  = (const float*)d_in[1];
  const float* dkeys = (const float*)d_in[2];
  const float* dvals = (const float*)d_in[3];
  const float* Wqh   = (const float*)d_in[4];
  // d_in[5]=Wq, d_in[6]=Wk, d_in[8]=bq, d_in[9]=bk: dead (degenerate attention)
  const float* Wv    = (const float*)d_in[7];
  const float* bv    = (const float*)d_in[10];
  const float* Wo    = (const float*)d_in[11];
  const float* bo    = (const float*)d_in[12];
  const float* Wdoc  = (const float*)d_in[13];
  const float* gate  = (const float*)d_in[14];
  float* out = (float*)d_out;

  const size_t NEED = ((size_t)22 << 20) + 4096;
  if (ws_size < NEED){
    zero_out_kernel<<<NTOK*DDIM/1024, 256, 0, stream>>>(out);
    return;
  }

  // Workspace (22 MB + 4 KB):
  //  [0,4) qn  [4,5) dkn  [5,5.5) wsm  [5.5,6) idx
  //  [6,8) T1  [8,10) T2  [10,12) tmp
  //  [12,14) dkn16s (512 KB, written L1, read L2) then WcT (written L5, read L6)
  //  [14,22) P (bf16)   [22M,+4K) bc
  // d_out (64 MiB) scratch until output overwrites:
  //  [0,16) split-K4 f32 partials (G1/G2)
  //  [16,24) dv16   [24,26) wd16   [26,30) kbuf (4 MB)
  char* ws = (char*)d_ws;
  float* qn             = (float*)(ws);
  float* dkn            = (float*)(ws + ((size_t)4 << 20));
  float* wsm            = (float*)(ws + ((size_t)5 << 20));
  int*   idx            = (int*)  (ws + ((size_t)5 << 20) + (512 << 10));
  unsigned short* T1    = (unsigned short*)(ws + ((size_t)6  << 20));
  unsigned short* T2    = (unsigned short*)(ws + ((size_t)8  << 20));
  unsigned short* tmp   = (unsigned short*)(ws + ((size_t)10 << 20));
  unsigned short* WcT   = (unsigned short*)(ws + ((size_t)12 << 20));
  unsigned short* dkn16s= (unsigned short*)(ws + ((size_t)12 << 20)); // pre-WcT lifetime
  unsigned short* P     = (unsigned short*)(ws + ((size_t)14 << 20));
  float* bc             = (float*)(ws + ((size_t)22 << 20));
  char* dob             = (char*)d_out;
  float*          pbuf = (float*)dob;                                  // 16 MB
  unsigned short* dv16 = (unsigned short*)(dob + ((size_t)16 << 20));  // 8 MB
  unsigned short* wd16 = (unsigned short*)(dob + ((size_t)24 << 20));  // 2 MB
  unsigned int*   kbuf = (unsigned int*)(dob + ((size_t)26 << 20));    // 4 MB

  // L1: all preprocessing + norms (independent, inputs only)
  prep_norm_kernel<<<12304, 256, 0, stream>>>(dvals, dv16, Wdoc, wd16, Wv, T1, Wo, T2,
                                              bv, bo, bc, hexw, Wqh, qn, dkeys, dkn, dkn16s);
  // L2: G1 (Wdoc@Wv partials) + topk_part (MFMA filter) fused
  g1_part_kernel<<<256 + 2048, 256, 0, stream>>>(wd16, T1, pbuf, qn, dkn16s, kbuf);
  // L3: reduce partials -> tmp
  reduce4_bf16<<<1024, 256, 0, stream>>>(pbuf, tmp);
  // L4: G2 (tmp@Wo, transposed-store partials)
  g2_kernel<<<256, 256, 0, stream>>>(tmp, T2, pbuf);
  // L5: reduce partials -> WcT (overwrites dkn16s region; part done in L2)
  reduce4_bf16<<<1024, 256, 0, stream>>>(pbuf, WcT);
  // L6: G3 (P = dvals@Wc) + rescore (exact f32 top-8 + softmax) fused
  g3_rescore_kernel<<<256 + 4096, 256, 0, stream>>>(dv16, WcT, P, kbuf, qn, dkn, wsm, idx);
  // L7: out = x + sigmoid(gate) * (gather-combine(P) + bc)
  output_kernel<<<NTOK/2, 256, 0, stream>>>(x, wsm, idx, P, bc, gate, out);
}